// Round 13
// baseline (145.258 us; speedup 1.0000x reference)
//
#include <hip/hip_runtime.h>
#include <hip/hip_bf16.h>

#define HH 96
#define WW 96
#define HW 9216
#define NB 8

typedef __bf16 bf16x8 __attribute__((ext_vector_type(8)));
typedef float  f32x4  __attribute__((ext_vector_type(4)));

union BF8 { uint4 u; bf16x8 v; unsigned short s[8]; };

__device__ __forceinline__ unsigned short f2bf_bits(float f) {
    unsigned u = __float_as_uint(f);
    unsigned r = u + 0x7FFFu + ((u >> 16) & 1u);     // RNE
    return (unsigned short)(r >> 16);
}
__device__ __forceinline__ float bf2f(unsigned short s) {
    return __uint_as_float(((unsigned)s) << 16);
}
__device__ __forceinline__ unsigned pkbf(float a, float b) {   // v_cvt_pk_bf16_f32
    union { __hip_bfloat162 h; unsigned u; } c;
    c.h = __float22bfloat162_rn(make_float2(a, b));
    return c.u;
}

// bilinear setup: 4 clamped corner record offsets (in shorts) + 4 mask-folded weights
__device__ __forceinline__ void bl_setup(int h, int w, int r, int s, float oy, float ox,
                                         int* a, float* wg) {
    float sy = (float)(h + r) + oy;
    float sx = (float)(w + s) + ox;
    float fy = floorf(sy), fx = floorf(sx);
    int   y0 = (int)fy, x0 = (int)fx;
    int   y1 = y0 + 1, x1 = x0 + 1;
    float wy1 = sy - fy, wx1 = sx - fx;
    float wy0 = 1.f - wy1, wx0 = 1.f - wx1;
    float m00 = (y0 >= 0 && y0 < HH && x0 >= 0 && x0 < WW) ? 1.f : 0.f;
    float m01 = (y0 >= 0 && y0 < HH && x1 >= 0 && x1 < WW) ? 1.f : 0.f;
    float m10 = (y1 >= 0 && y1 < HH && x0 >= 0 && x0 < WW) ? 1.f : 0.f;
    float m11 = (y1 >= 0 && y1 < HH && x1 >= 0 && x1 < WW) ? 1.f : 0.f;
    int cy0 = min(max(y0, 0), HH - 1), cy1 = min(max(y1, 0), HH - 1);
    int cx0 = min(max(x0, 0), WW - 1), cx1 = min(max(x1, 0), WW - 1);
    a[0] = (cy0 * WW + cx0) * 64;  a[1] = (cy0 * WW + cx1) * 64;
    a[2] = (cy1 * WW + cx0) * 64;  a[3] = (cy1 * WW + cx1) * 64;
    wg[0] = wy0 * wx0 * m00;  wg[1] = wy0 * wx1 * m01;
    wg[2] = wy1 * wx0 * m10;  wg[3] = wy1 * wx1 * m11;
}

// ---------------------------------------------------------------------------
// Kernel 1: x NCHW fp32 -> xt NHWC bf16 (unchanged path). Blocks < 216 build
// B-fragment-ordered weights:
//   wTb2 [tap][ct(4)][kc(2)][qd(4)][ln(16)][ch(8)]  (36864)
//   owTb2[tap][jt(2)][kc(2)][qd(4)][ln(16)][ch(8)]  (18432, j>=18 zero)
// so a wave's B-frag load is one contiguous 1 KB burst (lane l -> +l*8).
// ---------------------------------------------------------------------------
__global__ __launch_bounds__(256) void xcvt_prep(const float* __restrict__ x,
                                                 const float* __restrict__ weight,
                                                 const float* __restrict__ off_w,
                                                 unsigned short* __restrict__ xt,
                                                 unsigned short* __restrict__ wTb2,
                                                 unsigned short* __restrict__ owTb2) {
    __shared__ unsigned short T[64 * 64];   // [px][8 chunks], chunk' = chunk ^ (px&7)
    int bid   = blockIdx.x;                 // 1152
    int t     = threadIdx.x;
    int b     = bid & 7;                    // XCD-affine
    int pbase = (bid >> 3) * 64;
    int pl    = t & 63;
    int q     = t >> 6;                     // c-group 0..3 (chunks 2q, 2q+1)

    const float* xp = x + ((size_t)(b * 64 + q * 16)) * HW + pbase + pl;
    unsigned short hb[16];
#pragma unroll
    for (int i = 0; i < 16; ++i) hb[i] = f2bf_bits(xp[(size_t)i * HW]);

    uint4 w0, w1;
    w0.x = hb[0]  | (hb[1]  << 16); w0.y = hb[2]  | (hb[3]  << 16);
    w0.z = hb[4]  | (hb[5]  << 16); w0.w = hb[6]  | (hb[7]  << 16);
    w1.x = hb[8]  | (hb[9]  << 16); w1.y = hb[10] | (hb[11] << 16);
    w1.z = hb[12] | (hb[13] << 16); w1.w = hb[14] | (hb[15] << 16);
    int sw = pl & 7;
    *(uint4*)&T[pl * 64 + (((2 * q)     ^ sw) << 3)] = w0;
    *(uint4*)&T[pl * 64 + (((2 * q + 1) ^ sw) << 3)] = w1;
    __syncthreads();

    int row = t >> 2, rs = row & 7;
    uint4 a  = *(const uint4*)&T[row * 64 + ((((t & 3) * 2)     ^ rs) << 3)];
    uint4 b2 = *(const uint4*)&T[row * 64 + ((((t & 3) * 2 + 1) ^ rs) << 3)];
    unsigned short* dst = xt + ((size_t)(b * HW + pbase)) * 64 + t * 16;
    *(uint4*)dst       = a;
    *(uint4*)(dst + 8) = b2;

    if (bid < 216) {                        // 216*256 = 36864 + 18432
        int i = bid * 256 + t;
        if (i < 36864) {
            int ch = i & 7, lnn = (i >> 3) & 15, qdd = (i >> 7) & 3;
            int kc = (i >> 9) & 1, ct = (i >> 10) & 3, tap = i >> 12;
            int co = ct * 16 + lnn;
            int c  = kc * 32 + qdd * 8 + ch;
            wTb2[i] = f2bf_bits(weight[(co * 64 + c) * 9 + tap]);
        } else {
            int f = i - 36864;
            int ch = f & 7, lnn = (f >> 3) & 15, qdd = (f >> 7) & 3;
            int kc = (f >> 9) & 1, jt = (f >> 10) & 1, tap = f >> 11;
            int j = jt * 16 + lnn;
            int c = kc * 32 + qdd * 8 + ch;
            owTb2[f] = (j < 18) ? f2bf_bits(off_w[(j * 64 + c) * 9 + tap]) : (unsigned short)0;
        }
    }
}

// ---------------------------------------------------------------------------
// Kernel 2 (fused, ZERO barriers): wave = 16 pixels, fully independent.
// Lane l = (px = l&15, k-chunk qd = l>>4). A-fragments are loaded/built
// directly in registers (per-frag load = 16 records x 64 B = 1 KB/instr,
// the L1 BW optimum). Phase A: patch-MFMA vs owTb2 -> offsets via wave-local
// LDS transpose (no __syncthreads needed: DS ops are wave-ordered).
// Phase B: bilinear combine in registers -> MFMA vs wTb2. No staging LDS.
// ---------------------------------------------------------------------------
__global__ __launch_bounds__(256) void deform_all(const unsigned short* __restrict__ xt,
                                                  const unsigned short* __restrict__ wTb2,
                                                  const unsigned short* __restrict__ owTb2,
                                                  const float* __restrict__ bias,
                                                  const float* __restrict__ ob,
                                                  float* __restrict__ out) {
    __shared__ float offs[4][16 * 20];      // per-wave private [px][18 j + pad]

    int bid   = blockIdx.x;                 // 1152
    int t     = threadIdx.x;
    int b     = bid & 7;                    // image per XCD
    int wv    = t >> 6;
    int l     = t & 63;
    int ln    = l & 15;                     // pixel within the wave's 16-px tile
    int qd    = l >> 4;                     // k-chunk (8 channels)
    int pbase = (bid >> 3) * 64 + wv * 16;  // wave's pixel base
    int px    = pbase + ln;
    int h     = px / WW, w = px - h * WW;

    const unsigned short* xb = xt + (size_t)b * HW * 64;

    // ================= phase A: offset conv, register-direct =================
    f32x4 aj0 = {0.f, 0.f, 0.f, 0.f};
    f32x4 aj1 = {0.f, 0.f, 0.f, 0.f};
#pragma unroll
    for (int tap = 0; tap < 9; ++tap) {
        int  r  = tap / 3, s = tap - r * 3;
        int  iy = h - 1 + r, ix = w - 1 + s;
        bool vd = (iy >= 0) & (iy < HH) & (ix >= 0) & (ix < WW);
        int  rec = (min(max(iy, 0), HH - 1) * WW + min(max(ix, 0), WW - 1)) * 64;
        BF8 a0, a1;
        a0.u = *(const uint4*)(xb + rec + qd * 8);        // channels qd*8..+7
        a1.u = *(const uint4*)(xb + rec + 32 + qd * 8);   // channels 32+qd*8..+7
        if (!vd) { a0.u = make_uint4(0,0,0,0); a1.u = make_uint4(0,0,0,0); }

        const unsigned short* base0 = owTb2 + (size_t)tap * 2048 + l * 8;
        BF8 b00, b01, b10, b11;                            // [jt][kc]
        b00.u = *(const uint4*)(base0);
        b01.u = *(const uint4*)(base0 + 512);
        b10.u = *(const uint4*)(base0 + 1024);
        b11.u = *(const uint4*)(base0 + 1536);
        aj0 = __builtin_amdgcn_mfma_f32_16x16x32_bf16(a0.v, b00.v, aj0, 0, 0, 0);
        aj0 = __builtin_amdgcn_mfma_f32_16x16x32_bf16(a1.v, b01.v, aj0, 0, 0, 0);
        aj1 = __builtin_amdgcn_mfma_f32_16x16x32_bf16(a0.v, b10.v, aj1, 0, 0, 0);
        aj1 = __builtin_amdgcn_mfma_f32_16x16x32_bf16(a1.v, b11.v, aj1, 0, 0, 0);
    }

    // wave-local transpose: D (col=j, row=px_local=qd*4+rg) -> offs[px][j]
    {
        float* ow_ = offs[wv];
        float  obj = ob[ln];
#pragma unroll
        for (int rg = 0; rg < 4; ++rg) ow_[(qd * 4 + rg) * 20 + ln] = aj0[rg] + obj;
        if (ln < 2) {
            float obj1 = ob[16 + ln];
#pragma unroll
            for (int rg = 0; rg < 4; ++rg) ow_[(qd * 4 + rg) * 20 + 16 + ln] = aj1[rg] + obj1;
        }
    }
    // read own pixel's 9 offset pairs (DS in wave order -> no barrier needed)
    float oy[9], ox[9];
#pragma unroll
    for (int k = 0; k < 9; ++k) {
        float2 p = *(const float2*)&offs[wv][ln * 20 + 2 * k];
        oy[k] = p.x; ox[k] = p.y;
    }

    // ================= phase B: sample + main MFMA, all registers =============
    f32x4 acc[4] = {{0.f,0.f,0.f,0.f},{0.f,0.f,0.f,0.f},{0.f,0.f,0.f,0.f},{0.f,0.f,0.f,0.f}};

#pragma unroll
    for (int tap = 0; tap < 9; ++tap) {
        int r = tap / 3, s = tap - r * 3;
        int   aa[4];
        float gg[4];
        bl_setup(h, w, r, s, oy[tap], ox[tap], aa, gg);

        // 8 corner-frag loads (each: 16 records x 64 B = 1 KB/instr)
        BF8 f0[4], f1[4];
#pragma unroll
        for (int c = 0; c < 4; ++c) {
            f0[c].u = *(const uint4*)(xb + aa[c] + qd * 8);
            f1[c].u = *(const uint4*)(xb + aa[c] + 32 + qd * 8);
        }

        // bilinear combine in fp32 -> bf16 A-frags (already in MFMA layout)
        BF8 A0, A1;
        {
            float v0[8], v1[8];
#pragma unroll
            for (int i = 0; i < 8; ++i) {
                v0[i] = gg[0] * bf2f(f0[0].s[i]) + gg[1] * bf2f(f0[1].s[i])
                      + gg[2] * bf2f(f0[2].s[i]) + gg[3] * bf2f(f0[3].s[i]);
                v1[i] = gg[0] * bf2f(f1[0].s[i]) + gg[1] * bf2f(f1[1].s[i])
                      + gg[2] * bf2f(f1[2].s[i]) + gg[3] * bf2f(f1[3].s[i]);
            }
            A0.u.x = pkbf(v0[0], v0[1]); A0.u.y = pkbf(v0[2], v0[3]);
            A0.u.z = pkbf(v0[4], v0[5]); A0.u.w = pkbf(v0[6], v0[7]);
            A1.u.x = pkbf(v1[0], v1[1]); A1.u.y = pkbf(v1[2], v1[3]);
            A1.u.z = pkbf(v1[4], v1[5]); A1.u.w = pkbf(v1[6], v1[7]);
        }

        // 4 co-tiles x 2 k-chunks; B-frags = contiguous 1 KB bursts from L1
        const unsigned short* wb = wTb2 + (size_t)tap * 4096 + l * 8;
#pragma unroll
        for (int ct = 0; ct < 4; ++ct) {
            BF8 B0, B1;
            B0.u = *(const uint4*)(wb + ct * 1024);
            B1.u = *(const uint4*)(wb + ct * 1024 + 512);
            acc[ct] = __builtin_amdgcn_mfma_f32_16x16x32_bf16(A0.v, B0.v, acc[ct], 0, 0, 0);
            acc[ct] = __builtin_amdgcn_mfma_f32_16x16x32_bf16(A1.v, B1.v, acc[ct], 0, 0, 0);
        }
    }

    // ---- epilogue: D col = co (ct*16+ln), rows px = qd*4+rg ----
#pragma unroll
    for (int ct = 0; ct < 4; ++ct) {
        int   co = ct * 16 + ln;
        float bv = bias[co];
        float4 st;
        st.x = acc[ct][0] + bv; st.y = acc[ct][1] + bv;
        st.z = acc[ct][2] + bv; st.w = acc[ct][3] + bv;
        *(float4*)(out + ((size_t)(b * 64 + co)) * HW + pbase + qd * 4) = st;
    }
}

// ---------------------------------------------------------------------------
extern "C" void kernel_launch(void* const* d_in, const int* in_sizes, int n_in,
                              void* d_out, int out_size, void* d_ws, size_t ws_size,
                              hipStream_t stream) {
    const float* x      = (const float*)d_in[0];   // 8*64*96*96
    const float* weight = (const float*)d_in[1];   // 64*64*3*3
    const float* bias   = (const float*)d_in[2];   // 64
    const float* off_w  = (const float*)d_in[3];   // 18*64*3*3
    const float* off_b  = (const float*)d_in[4];   // 18
    float* out = (float*)d_out;

    unsigned short* xt    = (unsigned short*)d_ws; // 4,718,592 bf16
    unsigned short* wTb2  = xt + 4718592;          // 36,864 bf16 (frag-ordered)
    unsigned short* owTb2 = wTb2 + 36864;          // 18,432 bf16 (frag-ordered)

    hipLaunchKernelGGL(xcvt_prep,  dim3(1152), dim3(256), 0, stream,
                       x, weight, off_w, xt, wTb2, owTb2);
    hipLaunchKernelGGL(deform_all, dim3(1152), dim3(256), 0, stream,
                       xt, wTb2, owTb2, bias, off_b, out);
}